// Round 6
// baseline (630.659 us; speedup 1.0000x reference)
//
#include <hip/hip_runtime.h>

#define T_TOK 4096
#define H_DIM 512
#define F_DIM 2048
#define N_EXP 16
#define N_SH  2
#define TOPK  4

typedef __attribute__((ext_vector_type(4))) float f32x4;
typedef __attribute__((ext_vector_type(8))) short bf16x8;

__device__ __forceinline__ unsigned short f2bf(float f){
  union { float f; unsigned u; } a; a.f = f;
  unsigned u = a.u;
  return (unsigned short)((u + 0x7fffu + ((u >> 16) & 1u)) >> 16);
}

// exp-based tanh-GELU: |err| < ~1e-3 abs, far under the bf16-h quantization.
__device__ __forceinline__ float fast_gelu(float v){
  float u = 0.7978845608f * (v + 0.044715f * v * v * v);
  u = fminf(fmaxf(u, -15.f), 15.f);
  float e = __expf(2.f * u);
  float th = (e - 1.f) * __builtin_amdgcn_rcpf(e + 1.f);
  return 0.5f * v * (1.f + th);
}

#define GLD16(gsrc, ldst) \
  __builtin_amdgcn_global_load_lds((const __attribute__((address_space(1))) unsigned int*)(gsrc), \
                                   (__attribute__((address_space(3))) unsigned int*)(ldst), 16, 0, 0)

// ---------------- transpose + convert: src[R][C] f32 -> dst[C][R] bf16 (routed+shared fused) ----------------
__global__ void moe_transpose2(const float* __restrict__ s0, const float* __restrict__ s1,
                               unsigned short* __restrict__ d0, unsigned short* __restrict__ d1,
                               int R, int C){
  __shared__ float tile[64][65];
  int z = blockIdx.z;
  size_t per = (size_t)R * C;
  const float* src      = (z < N_EXP) ? s0 + (size_t)z * per : s1 + (size_t)(z - N_EXP) * per;
  unsigned short* dst   = (z < N_EXP) ? d0 + (size_t)z * per : d1 + (size_t)(z - N_EXP) * per;
  int c0 = blockIdx.x * 64, r0 = blockIdx.y * 64;
  int t = threadIdx.x;
  #pragma unroll
  for (int i = 0; i < 16; ++i){
    int idx = i * 256 + t; int r = idx >> 6, c = idx & 63;
    tile[r][c] = src[(size_t)(r0 + r) * C + (c0 + c)];
  }
  __syncthreads();
  #pragma unroll
  for (int i = 0; i < 16; ++i){
    int idx = i * 256 + t; int r = idx >> 6, c = idx & 63;
    dst[(size_t)(c0 + r) * R + (r0 + c)] = f2bf(tile[c][r]);
  }
}

// ---------------- gating (fp32, 4 lanes per token) + x->bf16 conversion fused ----------------
// Round-5 theory: 16-block gate left 240 CUs idle + 8192 scalar LDS reads/thread.
// Now: 64 blocks, token = 64/block, H split across 4 lanes, float4 LDS reads
// from a 132-float-pitch layout (quads hit 4 distinct bank groups), shfl reduce.
__global__ __launch_bounds__(256) void moe_gate(
    const float* __restrict__ x, const float* __restrict__ gw,
    unsigned short* __restrict__ xb,
    int* __restrict__ tki, float* __restrict__ tkw,
    int* __restrict__ counts){
  __shared__ float gwl[64 * 132];               // 33 KB, pitch 132 per 128-float quarter
  int tid = threadIdx.x;
  #pragma unroll
  for (int j = 0; j < 32; ++j){
    int s = j * 256 + tid;                       // source index into gw[8192]
    gwl[(s >> 7) * 132 + (s & 127)] = gw[s];
  }
  __syncthreads();

  int t = blockIdx.x * 64 + (tid >> 2);          // token
  int q = tid & 3;                               // H-quarter (128 floats)
  const float4* xr = (const float4*)(x  + (size_t)t * H_DIM + q * 128);
  ushort4*      xw = (ushort4*)     (xb + (size_t)t * H_DIM + q * 128);
  float acc[N_EXP];
  #pragma unroll
  for (int e = 0; e < N_EXP; ++e) acc[e] = 0.f;
  for (int i = 0; i < 32; ++i){
    float4 xv = xr[i];
    ushort4 o; o.x = f2bf(xv.x); o.y = f2bf(xv.y); o.z = f2bf(xv.z); o.w = f2bf(xv.w);
    xw[i] = o;
    #pragma unroll
    for (int e = 0; e < N_EXP; ++e){
      float4 wv = *(const float4*)&gwl[((e << 2) + q) * 132 + (i << 2)];
      acc[e] += xv.x * wv.x + xv.y * wv.y + xv.z * wv.z + xv.w * wv.w;
    }
  }
  // reduce across the 4 quarter-lanes
  #pragma unroll
  for (int e = 0; e < N_EXP; ++e){
    acc[e] += __shfl_xor(acc[e], 1);
    acc[e] += __shfl_xor(acc[e], 2);
  }
  if (q == 0){
    float m = -1e30f;
    #pragma unroll
    for (int e = 0; e < N_EXP; ++e) m = fmaxf(m, acc[e]);
    float Z = 0.f;
    #pragma unroll
    for (int e = 0; e < N_EXP; ++e){ acc[e] = __expf(acc[e] - m); Z += acc[e]; }
    float inv = 1.f / Z;
    #pragma unroll
    for (int e = 0; e < N_EXP; ++e) acc[e] *= inv;
    int sel[TOPK]; float sv[TOPK];
    unsigned used = 0;
    #pragma unroll
    for (int k = 0; k < TOPK; ++k){
      int best = 0; float bv = -1.f;
      #pragma unroll
      for (int e = 0; e < N_EXP; ++e)
        if (!((used >> e) & 1u) && acc[e] > bv){ bv = acc[e]; best = e; }
      used |= 1u << best; sel[k] = best; sv[k] = bv;
    }
    float m0 = sv[0];                            // save max BEFORE exp loop!
    float Z2 = 0.f;
    #pragma unroll
    for (int k = 0; k < TOPK; ++k){ sv[k] = __expf(sv[k] - m0); Z2 += sv[k]; }
    float i2 = 1.f / Z2;
    #pragma unroll
    for (int k = 0; k < TOPK; ++k){
      tki[t * TOPK + k] = sel[k];
      tkw[t * TOPK + k] = sv[k] * i2;
      atomicAdd(&counts[sel[k]], 1);
    }
  }
}

// ---------------- prefix offsets (1 thread) ----------------
__global__ void moe_offsets(const int* __restrict__ counts, int* __restrict__ offs,
                            int* __restrict__ cursor){
  if (threadIdx.x == 0){
    int a = 0;
    for (int e = 0; e < N_EXP; ++e){ offs[e] = a; cursor[e] = a; a += counts[e]; }
  }
}

// ---------------- build per-expert row lists ----------------
__global__ void moe_build_rows(const int* __restrict__ tki, const float* __restrict__ tkw,
                               int* __restrict__ cursor, int* __restrict__ rows,
                               float* __restrict__ roww){
  int t = blockIdx.x * 256 + threadIdx.x;
  if (t >= T_TOK) return;
  for (int k = 0; k < TOPK; ++k){
    int e = tki[t * TOPK + k];
    int pos = atomicAdd(&cursor[e], 1);
    rows[pos] = t;
    roww[pos] = tkw[t * TOPK + k];
  }
}

// ---------------- grouped GEMM1: h = gelu(X @ W1 + b1), bf16 out ----------------
// 1D grid, logical (job, m, n) with n fastest; chunked XCD swizzle so each
// XCD's chunk covers whole experts (A+W fit its private L2). nwg=9216, %8==0.
__global__ __launch_bounds__(256, 4) void moe_gemm1(
    const unsigned short* __restrict__ xb,
    const unsigned short* __restrict__ rw1T,   // [E][F][H]
    const unsigned short* __restrict__ sw1T,   // [2][F][H]
    const float* __restrict__ rb1, const float* __restrict__ sb1,
    const int* __restrict__ counts, const int* __restrict__ offs,
    const int* __restrict__ rows,
    unsigned short* __restrict__ h_rout, unsigned short* __restrict__ h_sh){
  constexpr int K  = H_DIM;   // 512
  constexpr int NK = K / 64;  // 8
  constexpr int CPX = (18 * 32 * 16) / 8;      // 1152
  int L = (blockIdx.x & 7) * CPX + (blockIdx.x >> 3);
  int n  = L & 15;
  int mi = (L >> 4) & 31;
  int job = L >> 9;

  int M; const int* rmap; const unsigned short* wT; const float* bias; unsigned short* hout;
  if (job < N_EXP){
    M = counts[job];
    int base = offs[job];
    rmap = rows + base;
    wT = rw1T + (size_t)job * F_DIM * H_DIM;
    bias = rb1 + job * F_DIM;
    hout = h_rout + (size_t)base * F_DIM;
  } else {
    int s = job - N_EXP;
    M = T_TOK; rmap = nullptr;
    wT = sw1T + (size_t)s * F_DIM * H_DIM;
    bias = sb1 + s * F_DIM;
    hout = h_sh + (size_t)s * T_TOK * F_DIM;
  }
  int m0 = mi * 128;
  if (m0 >= M) return;
  int n0 = n * 128;

  __shared__ char smem[32768];
  int tid = threadIdx.x;
  int wave = tid >> 6, lane = tid & 63;
  int wm = wave >> 1, wn = wave & 1;

  const unsigned short* asrc[4];
  const unsigned short* bsrc[4];
  int srow = tid >> 3;   // 0..31
  int slot = tid & 7;
  #pragma unroll
  for (int r = 0; r < 4; ++r){
    int row = r * 32 + srow;
    int gr = m0 + row; if (gr > M - 1) gr = M - 1;
    int tok = rmap ? rmap[gr] : gr;
    asrc[r] = xb + (size_t)tok * H_DIM + ((slot ^ (row & 7)) << 3);
    bsrc[r] = wT + (size_t)(n0 + row) * K + ((slot ^ (row & 7)) << 3);
  }

  f32x4 acc[4][4];
  #pragma unroll
  for (int i = 0; i < 4; ++i)
    #pragma unroll
    for (int j = 0; j < 4; ++j) acc[i][j] = (f32x4)0.f;

  auto stage = [&](int k0){
    #pragma unroll
    for (int r = 0; r < 4; ++r) GLD16(asrc[r] + k0, smem + r * 4096 + wave * 1024);
    #pragma unroll
    for (int r = 0; r < 4; ++r) GLD16(bsrc[r] + k0, smem + 16384 + r * 4096 + wave * 1024);
  };

  for (int kt = 0; kt < NK; ++kt){
    if (kt) __syncthreads();
    stage(kt * 64);
    __syncthreads();
    const char* A = smem;
    const char* B = A + 16384;
    #pragma unroll
    for (int ks = 0; ks < 2; ++ks){
      int kg = ks * 4 + (lane >> 4);
      bf16x8 a[4], b[4];
      #pragma unroll
      for (int f = 0; f < 4; ++f){
        int row = wm * 64 + f * 16 + (lane & 15);
        a[f] = *(const bf16x8*)(A + row * 128 + ((kg ^ (row & 7)) << 4));
      }
      #pragma unroll
      for (int f = 0; f < 4; ++f){
        int row = wn * 64 + f * 16 + (lane & 15);
        b[f] = *(const bf16x8*)(B + row * 128 + ((kg ^ (row & 7)) << 4));
      }
      #pragma unroll
      for (int fm = 0; fm < 4; ++fm)
        #pragma unroll
        for (int fn = 0; fn < 4; ++fn)
          acc[fm][fn] = __builtin_amdgcn_mfma_f32_16x16x32_bf16(a[fm], b[fn], acc[fm][fn], 0, 0, 0);
    }
  }

  #pragma unroll
  for (int fm = 0; fm < 4; ++fm){
    #pragma unroll
    for (int j = 0; j < 4; ++j){
      int row = wm * 64 + fm * 16 + (lane >> 4) * 4 + j;
      int gr = m0 + row;
      if (gr < M){
        #pragma unroll
        for (int fn = 0; fn < 4; ++fn){
          int col = n0 + wn * 64 + fn * 16 + (lane & 15);
          float v = acc[fm][fn][j] + bias[col];
          hout[(size_t)gr * F_DIM + col] = f2bf(fast_gelu(v));
        }
      }
    }
  }
}

// ---------------- grouped GEMM2: out += wgt * (H @ W2 + b2) ----------------
// nwg = 18*32*4 = 2304, %8==0; n fastest (A-tile reused across the 4 n-tiles).
__global__ __launch_bounds__(256, 4) void moe_gemm2(
    const unsigned short* __restrict__ h_rout,
    const unsigned short* __restrict__ h_sh,
    const unsigned short* __restrict__ rw2T,   // [E][H][F]
    const unsigned short* __restrict__ sw2T,   // [2][H][F]
    const float* __restrict__ rb2, const float* __restrict__ sb2,
    const int* __restrict__ counts, const int* __restrict__ offs,
    const int* __restrict__ rows, const float* __restrict__ roww,
    float* __restrict__ out){
  constexpr int K  = F_DIM;   // 2048
  constexpr int NK = K / 64;  // 32
  constexpr int CPX = (18 * 32 * 4) / 8;       // 288
  int L = (blockIdx.x & 7) * CPX + (blockIdx.x >> 3);
  int n  = L & 3;
  int mi = (L >> 2) & 31;
  int job = L >> 7;

  int M; const unsigned short* aseg; const unsigned short* wT; const float* bias;
  const int* rmap; const float* rwt;
  if (job < N_EXP){
    M = counts[job];
    int base = offs[job];
    aseg = h_rout + (size_t)base * F_DIM;
    rmap = rows + base; rwt = roww + base;
    wT = rw2T + (size_t)job * H_DIM * F_DIM;
    bias = rb2 + job * H_DIM;
  } else {
    int s = job - N_EXP; M = T_TOK;
    aseg = h_sh + (size_t)s * T_TOK * F_DIM;
    rmap = nullptr; rwt = nullptr;
    wT = sw2T + (size_t)s * H_DIM * F_DIM;
    bias = sb2 + s * H_DIM;
  }
  int m0 = mi * 128;
  if (m0 >= M) return;
  int n0 = n * 128;

  __shared__ char smem[32768];
  int tid = threadIdx.x;
  int wave = tid >> 6, lane = tid & 63;
  int wm = wave >> 1, wn = wave & 1;

  const unsigned short* asrc[4];
  const unsigned short* bsrc[4];
  int srow = tid >> 3;
  int slot = tid & 7;
  #pragma unroll
  for (int r = 0; r < 4; ++r){
    int row = r * 32 + srow;
    int gr = m0 + row; if (gr > M - 1) gr = M - 1;
    asrc[r] = aseg + (size_t)gr * K + ((slot ^ (row & 7)) << 3);
    bsrc[r] = wT + (size_t)(n0 + row) * K + ((slot ^ (row & 7)) << 3);
  }

  f32x4 acc[4][4];
  #pragma unroll
  for (int i = 0; i < 4; ++i)
    #pragma unroll
    for (int j = 0; j < 4; ++j) acc[i][j] = (f32x4)0.f;

  auto stage = [&](int k0){
    #pragma unroll
    for (int r = 0; r < 4; ++r) GLD16(asrc[r] + k0, smem + r * 4096 + wave * 1024);
    #pragma unroll
    for (int r = 0; r < 4; ++r) GLD16(bsrc[r] + k0, smem + 16384 + r * 4096 + wave * 1024);
  };

  for (int kt = 0; kt < NK; ++kt){
    if (kt) __syncthreads();
    stage(kt * 64);
    __syncthreads();
    const char* A = smem;
    const char* B = A + 16384;
    #pragma unroll
    for (int ks = 0; ks < 2; ++ks){
      int kg = ks * 4 + (lane >> 4);
      bf16x8 a[4], b[4];
      #pragma unroll
      for (int f = 0; f < 4; ++f){
        int row = wm * 64 + f * 16 + (lane & 15);
        a[f] = *(const bf16x8*)(A + row * 128 + ((kg ^ (row & 7)) << 4));
      }
      #pragma unroll
      for (int f = 0; f < 4; ++f){
        int row = wn * 64 + f * 16 + (lane & 15);
        b[f] = *(const bf16x8*)(B + row * 128 + ((kg ^ (row & 7)) << 4));
      }
      #pragma unroll
      for (int fm = 0; fm < 4; ++fm)
        #pragma unroll
        for (int fn = 0; fn < 4; ++fn)
          acc[fm][fn] = __builtin_amdgcn_mfma_f32_16x16x32_bf16(a[fm], b[fn], acc[fm][fn], 0, 0, 0);
    }
  }

  #pragma unroll
  for (int fm = 0; fm < 4; ++fm){
    #pragma unroll
    for (int j = 0; j < 4; ++j){
      int row = wm * 64 + fm * 16 + (lane >> 4) * 4 + j;
      int gr = m0 + row;
      if (gr < M){
        int tok; float coef;
        if (rmap){ tok = rmap[gr]; coef = rwt[gr]; }
        else     { tok = gr;       coef = 1.0f / N_SH; }
        #pragma unroll
        for (int fn = 0; fn < 4; ++fn){
          int col = n0 + wn * 64 + fn * 16 + (lane & 15);
          float v = (acc[fm][fn][j] + bias[col]) * coef;
          atomicAdd(&out[(size_t)tok * H_DIM + col], v);
        }
      }
    }
  }
}

// ---------------- host launcher ----------------
extern "C" void kernel_launch(void* const* d_in, const int* in_sizes, int n_in,
                              void* d_out, int out_size, void* d_ws, size_t ws_size,
                              hipStream_t stream){
  const float* x   = (const float*)d_in[0];
  const float* gw  = (const float*)d_in[1];
  const float* rw1 = (const float*)d_in[2];
  const float* rb1 = (const float*)d_in[3];
  const float* rw2 = (const float*)d_in[4];
  const float* rb2 = (const float*)d_in[5];
  const float* sw1 = (const float*)d_in[6];
  const float* sb1 = (const float*)d_in[7];
  const float* sw2 = (const float*)d_in[8];
  const float* sb2 = (const float*)d_in[9];
  float* out = (float*)d_out;

  char* ws = (char*)d_ws;
  size_t off = 0;
  auto alloc = [&](size_t b){ size_t r = off; off += (b + 255) & ~(size_t)255; return r; };
  unsigned short* xb     = (unsigned short*)(ws + alloc((size_t)T_TOK * H_DIM * 2));
  unsigned short* rw1T   = (unsigned short*)(ws + alloc((size_t)N_EXP * H_DIM * F_DIM * 2));
  unsigned short* rw2T   = (unsigned short*)(ws + alloc((size_t)N_EXP * H_DIM * F_DIM * 2));
  unsigned short* sw1T   = (unsigned short*)(ws + alloc((size_t)N_SH * H_DIM * F_DIM * 2));
  unsigned short* sw2T   = (unsigned short*)(ws + alloc((size_t)N_SH * H_DIM * F_DIM * 2));
  unsigned short* h_rout = (unsigned short*)(ws + alloc((size_t)T_TOK * TOPK * F_DIM * 2));
  unsigned short* h_sh   = (unsigned short*)(ws + alloc((size_t)N_SH * T_TOK * F_DIM * 2));
  int*   counts = (int*)(ws + alloc(64));
  int*   offs   = (int*)(ws + alloc(64));
  int*   cursor = (int*)(ws + alloc(64));
  int*   tki    = (int*)(ws + alloc((size_t)T_TOK * TOPK * 4));
  float* tkw    = (float*)(ws + alloc((size_t)T_TOK * TOPK * 4));
  int*   rowsl  = (int*)(ws + alloc((size_t)T_TOK * TOPK * 4));
  float* roww   = (float*)(ws + alloc((size_t)T_TOK * TOPK * 4));

  hipMemsetAsync(counts, 0, 64, stream);
  hipMemsetAsync(out, 0, (size_t)T_TOK * H_DIM * 4, stream);

  moe_gate<<<T_TOK / 64, 256, 0, stream>>>(x, gw, xb, tki, tkw, counts);

  moe_transpose2<<<dim3(F_DIM / 64, H_DIM / 64, N_EXP + N_SH), 256, 0, stream>>>(
      rw1, sw1, rw1T, sw1T, H_DIM, F_DIM);
  moe_transpose2<<<dim3(H_DIM / 64, F_DIM / 64, N_EXP + N_SH), 256, 0, stream>>>(
      rw2, sw2, rw2T, sw2T, F_DIM, H_DIM);

  moe_offsets<<<1, 64, 0, stream>>>(counts, offs, cursor);
  moe_build_rows<<<T_TOK / 256, 256, 0, stream>>>(tki, tkw, cursor, rowsl, roww);

  moe_gemm1<<<18 * 32 * 16, 256, 0, stream>>>(
      xb, rw1T, sw1T, rb1, sb1, counts, offs, rowsl, h_rout, h_sh);
  moe_gemm2<<<18 * 32 * 4, 256, 0, stream>>>(
      h_rout, h_sh, rw2T, sw2T, rb2, sb2, counts, offs, rowsl, roww, out);
}

// Round 7
// 511.315 us; speedup vs baseline: 1.2334x; 1.2334x over previous
//
#include <hip/hip_runtime.h>

#define T_TOK 4096
#define H_DIM 512
#define F_DIM 2048
#define N_EXP 16
#define N_SH  2
#define TOPK  4

typedef __attribute__((ext_vector_type(4))) float f32x4;
typedef __attribute__((ext_vector_type(8))) short bf16x8;

__device__ __forceinline__ unsigned short f2bf(float f){
  union { float f; unsigned u; } a; a.f = f;
  unsigned u = a.u;
  return (unsigned short)((u + 0x7fffu + ((u >> 16) & 1u)) >> 16);
}

// exp-based tanh-GELU: |err| < ~1e-3 abs, far under the bf16-h quantization.
__device__ __forceinline__ float fast_gelu(float v){
  float u = 0.7978845608f * (v + 0.044715f * v * v * v);
  u = fminf(fmaxf(u, -15.f), 15.f);
  float e = __expf(2.f * u);
  float th = (e - 1.f) * __builtin_amdgcn_rcpf(e + 1.f);
  return 0.5f * v * (1.f + th);
}

#define GLD16(gsrc, ldst) \
  __builtin_amdgcn_global_load_lds((const __attribute__((address_space(1))) unsigned int*)(gsrc), \
                                   (__attribute__((address_space(3))) unsigned int*)(ldst), 16, 0, 0)

// ---------------- transpose + convert: src[R][C] f32 -> dst[C][R] bf16 (routed+shared fused) ----------------
__global__ void moe_transpose2(const float* __restrict__ s0, const float* __restrict__ s1,
                               unsigned short* __restrict__ d0, unsigned short* __restrict__ d1,
                               int R, int C){
  __shared__ float tile[64][65];
  int z = blockIdx.z;
  size_t per = (size_t)R * C;
  const float* src      = (z < N_EXP) ? s0 + (size_t)z * per : s1 + (size_t)(z - N_EXP) * per;
  unsigned short* dst   = (z < N_EXP) ? d0 + (size_t)z * per : d1 + (size_t)(z - N_EXP) * per;
  int c0 = blockIdx.x * 64, r0 = blockIdx.y * 64;
  int t = threadIdx.x;
  #pragma unroll
  for (int i = 0; i < 16; ++i){
    int idx = i * 256 + t; int r = idx >> 6, c = idx & 63;
    tile[r][c] = src[(size_t)(r0 + r) * C + (c0 + c)];
  }
  __syncthreads();
  #pragma unroll
  for (int i = 0; i < 16; ++i){
    int idx = i * 256 + t; int r = idx >> 6, c = idx & 63;
    dst[(size_t)(c0 + r) * R + (r0 + c)] = f2bf(tile[c][r]);
  }
}

// ---------------- gating (fp32, 4 lanes per token) + x->bf16 conversion fused ----------------
__global__ __launch_bounds__(256) void moe_gate(
    const float* __restrict__ x, const float* __restrict__ gw,
    unsigned short* __restrict__ xb,
    int* __restrict__ tki, float* __restrict__ tkw,
    int* __restrict__ counts){
  __shared__ float gwl[64 * 132];               // 33 KB, pitch 132 per 128-float quarter
  int tid = threadIdx.x;
  #pragma unroll
  for (int j = 0; j < 32; ++j){
    int s = j * 256 + tid;                       // source index into gw[8192]
    gwl[(s >> 7) * 132 + (s & 127)] = gw[s];
  }
  __syncthreads();

  int t = blockIdx.x * 64 + (tid >> 2);          // token
  int q = tid & 3;                               // H-quarter (128 floats)
  const float4* xr = (const float4*)(x  + (size_t)t * H_DIM + q * 128);
  ushort4*      xw = (ushort4*)     (xb + (size_t)t * H_DIM + q * 128);
  float acc[N_EXP];
  #pragma unroll
  for (int e = 0; e < N_EXP; ++e) acc[e] = 0.f;
  for (int i = 0; i < 32; ++i){
    float4 xv = xr[i];
    ushort4 o; o.x = f2bf(xv.x); o.y = f2bf(xv.y); o.z = f2bf(xv.z); o.w = f2bf(xv.w);
    xw[i] = o;
    #pragma unroll
    for (int e = 0; e < N_EXP; ++e){
      float4 wv = *(const float4*)&gwl[((e << 2) + q) * 132 + (i << 2)];
      acc[e] += xv.x * wv.x + xv.y * wv.y + xv.z * wv.z + xv.w * wv.w;
    }
  }
  // reduce across the 4 quarter-lanes
  #pragma unroll
  for (int e = 0; e < N_EXP; ++e){
    acc[e] += __shfl_xor(acc[e], 1);
    acc[e] += __shfl_xor(acc[e], 2);
  }
  if (q == 0){
    float m = -1e30f;
    #pragma unroll
    for (int e = 0; e < N_EXP; ++e) m = fmaxf(m, acc[e]);
    float Z = 0.f;
    #pragma unroll
    for (int e = 0; e < N_EXP; ++e){ acc[e] = __expf(acc[e] - m); Z += acc[e]; }
    float inv = 1.f / Z;
    #pragma unroll
    for (int e = 0; e < N_EXP; ++e) acc[e] *= inv;
    int sel[TOPK]; float sv[TOPK];
    unsigned used = 0;
    #pragma unroll
    for (int k = 0; k < TOPK; ++k){
      int best = 0; float bv = -1.f;
      #pragma unroll
      for (int e = 0; e < N_EXP; ++e)
        if (!((used >> e) & 1u) && acc[e] > bv){ bv = acc[e]; best = e; }
      used |= 1u << best; sel[k] = best; sv[k] = bv;
    }
    float m0 = sv[0];                            // save max BEFORE exp loop!
    float Z2 = 0.f;
    #pragma unroll
    for (int k = 0; k < TOPK; ++k){ sv[k] = __expf(sv[k] - m0); Z2 += sv[k]; }
    float i2 = 1.f / Z2;
    #pragma unroll
    for (int k = 0; k < TOPK; ++k){
      tki[t * TOPK + k] = sel[k];
      tkw[t * TOPK + k] = sv[k] * i2;
      atomicAdd(&counts[sel[k]], 1);
    }
  }
}

// ---------------- prefix offsets (1 thread) ----------------
__global__ void moe_offsets(const int* __restrict__ counts, int* __restrict__ offs,
                            int* __restrict__ cursor){
  if (threadIdx.x == 0){
    int a = 0;
    for (int e = 0; e < N_EXP; ++e){ offs[e] = a; cursor[e] = a; a += counts[e]; }
  }
}

// ---------------- build per-expert row lists ----------------
__global__ void moe_build_rows(const int* __restrict__ tki, const float* __restrict__ tkw,
                               int* __restrict__ cursor, int* __restrict__ rows,
                               float* __restrict__ roww){
  int t = blockIdx.x * 256 + threadIdx.x;
  if (t >= T_TOK) return;
  for (int k = 0; k < TOPK; ++k){
    int e = tki[t * TOPK + k];
    int pos = atomicAdd(&cursor[e], 1);
    rows[pos] = t;
    roww[pos] = tkw[t * TOPK + k];
  }
}

// Balanced XCD swizzle (round-6 lesson: chunked CPX put both shared experts on
// one XCD = 2.7x tail). xcd = b%8; all NT n-tiles of a slice are consecutive on
// that XCD (A-panel L2 reuse); slice = xcd + 8*u spreads every job's mi-slices
// evenly across XCDs (job*32 % 8 == 0 -> perfect static balance). Weights are
// read by all XCDs but stay L3-resident (108 MB < 256 MB).

// ---------------- grouped GEMM1: h = gelu(X @ W1 + b1), bf16 out ----------------
__global__ __launch_bounds__(256, 4) void moe_gemm1(
    const unsigned short* __restrict__ xb,
    const unsigned short* __restrict__ rw1T,   // [E][F][H]
    const unsigned short* __restrict__ sw1T,   // [2][F][H]
    const float* __restrict__ rb1, const float* __restrict__ sb1,
    const int* __restrict__ counts, const int* __restrict__ offs,
    const int* __restrict__ rows,
    unsigned short* __restrict__ h_rout, unsigned short* __restrict__ h_sh){
  constexpr int K  = H_DIM;   // 512
  constexpr int NK = K / 64;  // 8
  int xcd = blockIdx.x & 7;
  int i   = blockIdx.x >> 3;
  int n   = i & 15;            // NT=16 n-tiles, consecutive i on same XCD
  int u   = i >> 4;
  int slice = xcd + 8 * u;     // 0..575
  int mi  = slice & 31;
  int job = slice >> 5;

  int M; const int* rmap; const unsigned short* wT; const float* bias; unsigned short* hout;
  if (job < N_EXP){
    M = counts[job];
    int base = offs[job];
    rmap = rows + base;
    wT = rw1T + (size_t)job * F_DIM * H_DIM;
    bias = rb1 + job * F_DIM;
    hout = h_rout + (size_t)base * F_DIM;
  } else {
    int s = job - N_EXP;
    M = T_TOK; rmap = nullptr;
    wT = sw1T + (size_t)s * F_DIM * H_DIM;
    bias = sb1 + s * F_DIM;
    hout = h_sh + (size_t)s * T_TOK * F_DIM;
  }
  int m0 = mi * 128;
  if (m0 >= M) return;
  int n0 = n * 128;

  __shared__ char smem[32768];
  int tid = threadIdx.x;
  int wave = tid >> 6, lane = tid & 63;
  int wm = wave >> 1, wn = wave & 1;

  const unsigned short* asrc[4];
  const unsigned short* bsrc[4];
  int srow = tid >> 3;   // 0..31
  int slot = tid & 7;
  #pragma unroll
  for (int r = 0; r < 4; ++r){
    int row = r * 32 + srow;
    int gr = m0 + row; if (gr > M - 1) gr = M - 1;
    int tok = rmap ? rmap[gr] : gr;
    asrc[r] = xb + (size_t)tok * H_DIM + ((slot ^ (row & 7)) << 3);
    bsrc[r] = wT + (size_t)(n0 + row) * K + ((slot ^ (row & 7)) << 3);
  }

  f32x4 acc[4][4];
  #pragma unroll
  for (int i2 = 0; i2 < 4; ++i2)
    #pragma unroll
    for (int j = 0; j < 4; ++j) acc[i2][j] = (f32x4)0.f;

  auto stage = [&](int k0){
    #pragma unroll
    for (int r = 0; r < 4; ++r) GLD16(asrc[r] + k0, smem + r * 4096 + wave * 1024);
    #pragma unroll
    for (int r = 0; r < 4; ++r) GLD16(bsrc[r] + k0, smem + 16384 + r * 4096 + wave * 1024);
  };

  for (int kt = 0; kt < NK; ++kt){
    if (kt) __syncthreads();
    stage(kt * 64);
    __syncthreads();
    const char* A = smem;
    const char* B = A + 16384;
    #pragma unroll
    for (int ks = 0; ks < 2; ++ks){
      int kg = ks * 4 + (lane >> 4);
      bf16x8 a[4], b[4];
      #pragma unroll
      for (int f = 0; f < 4; ++f){
        int row = wm * 64 + f * 16 + (lane & 15);
        a[f] = *(const bf16x8*)(A + row * 128 + ((kg ^ (row & 7)) << 4));
      }
      #pragma unroll
      for (int f = 0; f < 4; ++f){
        int row = wn * 64 + f * 16 + (lane & 15);
        b[f] = *(const bf16x8*)(B + row * 128 + ((kg ^ (row & 7)) << 4));
      }
      #pragma unroll
      for (int fm = 0; fm < 4; ++fm)
        #pragma unroll
        for (int fn = 0; fn < 4; ++fn)
          acc[fm][fn] = __builtin_amdgcn_mfma_f32_16x16x32_bf16(a[fm], b[fn], acc[fm][fn], 0, 0, 0);
    }
  }

  #pragma unroll
  for (int fm = 0; fm < 4; ++fm){
    #pragma unroll
    for (int j = 0; j < 4; ++j){
      int row = wm * 64 + fm * 16 + (lane >> 4) * 4 + j;
      int gr = m0 + row;
      if (gr < M){
        #pragma unroll
        for (int fn = 0; fn < 4; ++fn){
          int col = n0 + wn * 64 + fn * 16 + (lane & 15);
          float v = acc[fm][fn][j] + bias[col];
          hout[(size_t)gr * F_DIM + col] = f2bf(fast_gelu(v));
        }
      }
    }
  }
}

// ---------------- grouped GEMM2: out += wgt * (H @ W2 + b2) ----------------
__global__ __launch_bounds__(256, 4) void moe_gemm2(
    const unsigned short* __restrict__ h_rout,
    const unsigned short* __restrict__ h_sh,
    const unsigned short* __restrict__ rw2T,   // [E][H][F]
    const unsigned short* __restrict__ sw2T,   // [2][H][F]
    const float* __restrict__ rb2, const float* __restrict__ sb2,
    const int* __restrict__ counts, const int* __restrict__ offs,
    const int* __restrict__ rows, const float* __restrict__ roww,
    float* __restrict__ out){
  constexpr int K  = F_DIM;   // 2048
  constexpr int NK = K / 64;  // 32
  int xcd = blockIdx.x & 7;
  int i   = blockIdx.x >> 3;
  int n   = i & 3;             // NT=4
  int u   = i >> 2;
  int slice = xcd + 8 * u;
  int mi  = slice & 31;
  int job = slice >> 5;

  int M; const unsigned short* aseg; const unsigned short* wT; const float* bias;
  const int* rmap; const float* rwt;
  if (job < N_EXP){
    M = counts[job];
    int base = offs[job];
    aseg = h_rout + (size_t)base * F_DIM;
    rmap = rows + base; rwt = roww + base;
    wT = rw2T + (size_t)job * H_DIM * F_DIM;
    bias = rb2 + job * H_DIM;
  } else {
    int s = job - N_EXP; M = T_TOK;
    aseg = h_sh + (size_t)s * T_TOK * F_DIM;
    rmap = nullptr; rwt = nullptr;
    wT = sw2T + (size_t)s * H_DIM * F_DIM;
    bias = sb2 + s * H_DIM;
  }
  int m0 = mi * 128;
  if (m0 >= M) return;
  int n0 = n * 128;

  __shared__ char smem[32768];
  int tid = threadIdx.x;
  int wave = tid >> 6, lane = tid & 63;
  int wm = wave >> 1, wn = wave & 1;

  const unsigned short* asrc[4];
  const unsigned short* bsrc[4];
  int srow = tid >> 3;
  int slot = tid & 7;
  #pragma unroll
  for (int r = 0; r < 4; ++r){
    int row = r * 32 + srow;
    int gr = m0 + row; if (gr > M - 1) gr = M - 1;
    asrc[r] = aseg + (size_t)gr * K + ((slot ^ (row & 7)) << 3);
    bsrc[r] = wT + (size_t)(n0 + row) * K + ((slot ^ (row & 7)) << 3);
  }

  f32x4 acc[4][4];
  #pragma unroll
  for (int i2 = 0; i2 < 4; ++i2)
    #pragma unroll
    for (int j = 0; j < 4; ++j) acc[i2][j] = (f32x4)0.f;

  auto stage = [&](int k0){
    #pragma unroll
    for (int r = 0; r < 4; ++r) GLD16(asrc[r] + k0, smem + r * 4096 + wave * 1024);
    #pragma unroll
    for (int r = 0; r < 4; ++r) GLD16(bsrc[r] + k0, smem + 16384 + r * 4096 + wave * 1024);
  };

  for (int kt = 0; kt < NK; ++kt){
    if (kt) __syncthreads();
    stage(kt * 64);
    __syncthreads();
    const char* A = smem;
    const char* B = A + 16384;
    #pragma unroll
    for (int ks = 0; ks < 2; ++ks){
      int kg = ks * 4 + (lane >> 4);
      bf16x8 a[4], b[4];
      #pragma unroll
      for (int f = 0; f < 4; ++f){
        int row = wm * 64 + f * 16 + (lane & 15);
        a[f] = *(const bf16x8*)(A + row * 128 + ((kg ^ (row & 7)) << 4));
      }
      #pragma unroll
      for (int f = 0; f < 4; ++f){
        int row = wn * 64 + f * 16 + (lane & 15);
        b[f] = *(const bf16x8*)(B + row * 128 + ((kg ^ (row & 7)) << 4));
      }
      #pragma unroll
      for (int fm = 0; fm < 4; ++fm)
        #pragma unroll
        for (int fn = 0; fn < 4; ++fn)
          acc[fm][fn] = __builtin_amdgcn_mfma_f32_16x16x32_bf16(a[fm], b[fn], acc[fm][fn], 0, 0, 0);
    }
  }

  #pragma unroll
  for (int fm = 0; fm < 4; ++fm){
    #pragma unroll
    for (int j = 0; j < 4; ++j){
      int row = wm * 64 + fm * 16 + (lane >> 4) * 4 + j;
      int gr = m0 + row;
      if (gr < M){
        int tok; float coef;
        if (rmap){ tok = rmap[gr]; coef = rwt[gr]; }
        else     { tok = gr;       coef = 1.0f / N_SH; }
        #pragma unroll
        for (int fn = 0; fn < 4; ++fn){
          int col = n0 + wn * 64 + fn * 16 + (lane & 15);
          float v = (acc[fm][fn][j] + bias[col]) * coef;
          atomicAdd(&out[(size_t)tok * H_DIM + col], v);
        }
      }
    }
  }
}

// ---------------- host launcher ----------------
extern "C" void kernel_launch(void* const* d_in, const int* in_sizes, int n_in,
                              void* d_out, int out_size, void* d_ws, size_t ws_size,
                              hipStream_t stream){
  const float* x   = (const float*)d_in[0];
  const float* gw  = (const float*)d_in[1];
  const float* rw1 = (const float*)d_in[2];
  const float* rb1 = (const float*)d_in[3];
  const float* rw2 = (const float*)d_in[4];
  const float* rb2 = (const float*)d_in[5];
  const float* sw1 = (const float*)d_in[6];
  const float* sb1 = (const float*)d_in[7];
  const float* sw2 = (const float*)d_in[8];
  const float* sb2 = (const float*)d_in[9];
  float* out = (float*)d_out;

  char* ws = (char*)d_ws;
  size_t off = 0;
  auto alloc = [&](size_t b){ size_t r = off; off += (b + 255) & ~(size_t)255; return r; };
  unsigned short* xb     = (unsigned short*)(ws + alloc((size_t)T_TOK * H_DIM * 2));
  unsigned short* rw1T   = (unsigned short*)(ws + alloc((size_t)N_EXP * H_DIM * F_DIM * 2));
  unsigned short* rw2T   = (unsigned short*)(ws + alloc((size_t)N_EXP * H_DIM * F_DIM * 2));
  unsigned short* sw1T   = (unsigned short*)(ws + alloc((size_t)N_SH * H_DIM * F_DIM * 2));
  unsigned short* sw2T   = (unsigned short*)(ws + alloc((size_t)N_SH * H_DIM * F_DIM * 2));
  unsigned short* h_rout = (unsigned short*)(ws + alloc((size_t)T_TOK * TOPK * F_DIM * 2));
  unsigned short* h_sh   = (unsigned short*)(ws + alloc((size_t)N_SH * T_TOK * F_DIM * 2));
  int*   counts = (int*)(ws + alloc(64));
  int*   offs   = (int*)(ws + alloc(64));
  int*   cursor = (int*)(ws + alloc(64));
  int*   tki    = (int*)(ws + alloc((size_t)T_TOK * TOPK * 4));
  float* tkw    = (float*)(ws + alloc((size_t)T_TOK * TOPK * 4));
  int*   rowsl  = (int*)(ws + alloc((size_t)T_TOK * TOPK * 4));
  float* roww   = (float*)(ws + alloc((size_t)T_TOK * TOPK * 4));

  hipMemsetAsync(counts, 0, 64, stream);
  hipMemsetAsync(out, 0, (size_t)T_TOK * H_DIM * 4, stream);

  moe_gate<<<T_TOK / 64, 256, 0, stream>>>(x, gw, xb, tki, tkw, counts);

  moe_transpose2<<<dim3(F_DIM / 64, H_DIM / 64, N_EXP + N_SH), 256, 0, stream>>>(
      rw1, sw1, rw1T, sw1T, H_DIM, F_DIM);
  moe_transpose2<<<dim3(H_DIM / 64, F_DIM / 64, N_EXP + N_SH), 256, 0, stream>>>(
      rw2, sw2, rw2T, sw2T, F_DIM, H_DIM);

  moe_offsets<<<1, 64, 0, stream>>>(counts, offs, cursor);
  moe_build_rows<<<T_TOK / 256, 256, 0, stream>>>(tki, tkw, cursor, rowsl, roww);

  moe_gemm1<<<18 * 32 * 16, 256, 0, stream>>>(
      xb, rw1T, sw1T, rb1, sb1, counts, offs, rowsl, h_rout, h_sh);
  moe_gemm2<<<18 * 32 * 4, 256, 0, stream>>>(
      h_rout, h_sh, rw2T, sw2T, rb2, sb2, counts, offs, rowsl, roww, out);
}